// Round 5
// baseline (239.245 us; speedup 1.0000x reference)
//
#include <hip/hip_runtime.h>

#define F_IN 128
#define F_ALL 128
#define F_HOP 64

#define RPB_BITS 9
#define RPB 512            // rows per bucket
#define KB_MAX 256         // max buckets (N <= 131072)
#define NBLK_BIN 256       // blocks for hist/bin kernels (== threads in blockscan)
#define ECAP 6144          // LDS edge-cache slots in sort kernel (48 KB)

typedef unsigned int uint;
typedef unsigned short ushort;
typedef __attribute__((ext_vector_type(8))) short short8v;
typedef __attribute__((ext_vector_type(4))) float float4v;

// ---------------------------------------------------------------- helpers
__device__ __forceinline__ uint pack_bf16(float lo, float hi) {
    uint ul = __float_as_uint(lo), uh = __float_as_uint(hi);
    ul += 0x7FFFu + ((ul >> 16) & 1u);
    uh += 0x7FFFu + ((uh >> 16) & 1u);
    return (ul >> 16) | (uh & 0xFFFF0000u);
}
__device__ __forceinline__ float bf_lo(uint h) { return __uint_as_float(h << 16); }
__device__ __forceinline__ float bf_hi(uint h) { return __uint_as_float(h & 0xFFFF0000u); }

// ---------------------------------------------------------------- MFMA GEMM + bf16 pack
__global__ __launch_bounds__(256) void gemm_mfma_kernel(
    const float* __restrict__ x, const float* __restrict__ W0,
    const float* __restrict__ W1, uint* __restrict__ H2, int N) {
    __shared__ ushort Wlds[16384];    // 4*8*64 fragments * 8 bf16 = 32 KB

    {
        const int t = threadIdx.x;
        #pragma unroll
        for (int i = 0; i < 8; ++i) {
            const int e    = t + 256 * i;
            const int lane = e & 63;
            const int tile = e >> 6;
            const int kt   = tile >> 3;
            const int nt   = tile & 7;
            const int k0   = kt * 32 + (lane >> 4) * 8;
            const int n    = nt * 16 + (lane & 15);
            const float* src = (n < 64) ? (W0 + n) : (W1 + (n - 64));
            float v[8];
            #pragma unroll
            for (int j = 0; j < 8; ++j) v[j] = src[(size_t)(k0 + j) * F_HOP];
            uint4 o;
            o.x = pack_bf16(v[0], v[1]);
            o.y = pack_bf16(v[2], v[3]);
            o.z = pack_bf16(v[4], v[5]);
            o.w = pack_bf16(v[6], v[7]);
            *((uint4*)Wlds + e) = o;
        }
    }
    __syncthreads();

    const int wv   = threadIdx.x >> 6;
    const int lane = threadIdx.x & 63;
    const int rbase = blockIdx.x * 64 + wv * 16;
    if (rbase >= N) return;

    const int m    = lane & 15;
    const int quad = lane >> 4;
    const float* xrow = x + (size_t)(rbase + m) * F_IN + quad * 8;

    float4v acc[8];
    #pragma unroll
    for (int t = 0; t < 8; ++t) acc[t] = (float4v){0.f, 0.f, 0.f, 0.f};

    #pragma unroll
    for (int kt = 0; kt < 4; ++kt) {
        // x is single-use: nontemporal keeps it from evicting H2 in L2/L3
        const float4v xa = __builtin_nontemporal_load((const float4v*)(xrow + kt * 32));
        const float4v xb = __builtin_nontemporal_load((const float4v*)(xrow + kt * 32 + 4));
        union { uint4 u; short8v s; } av;
        av.u.x = pack_bf16(xa[0], xa[1]);
        av.u.y = pack_bf16(xa[2], xa[3]);
        av.u.z = pack_bf16(xb[0], xb[1]);
        av.u.w = pack_bf16(xb[2], xb[3]);
        #pragma unroll
        for (int nt = 0; nt < 8; ++nt) {
            union { uint4 u; short8v s; } bv;
            bv.u = *((const uint4*)Wlds + (kt * 8 + nt) * 64 + lane);
            acc[nt] = __builtin_amdgcn_mfma_f32_16x16x32_bf16(av.s, bv.s, acc[nt], 0, 0, 0);
        }
    }

    #pragma unroll
    for (int t = 0; t < 4; ++t) {
        #pragma unroll
        for (int i = 0; i < 4; ++i) {
            const int r = rbase + quad * 4 + i;
            H2[(size_t)r * F_HOP + t * 16 + m] = pack_bf16(acc[t][i], acc[t + 4][i]);
        }
    }
}

// ---------------------------------------------------------------- CSR build, stage 1: bucket histogram
__global__ __launch_bounds__(256) void bucket_hist_kernel(
    const int* __restrict__ ei, int* __restrict__ bhist, int E, int K) {
    __shared__ int h[KB_MAX];
    for (int i = threadIdx.x; i < K; i += 256) h[i] = 0;
    __syncthreads();
    const int chunk = (E + NBLK_BIN - 1) / NBLK_BIN;
    const int s = blockIdx.x * chunk;
    const int e = min(s + chunk, E);
    for (int j = s + threadIdx.x; j < e; j += 256)
        atomicAdd(&h[__builtin_nontemporal_load(ei + j) >> RPB_BITS], 1);
    __syncthreads();
    for (int i = threadIdx.x; i < K; i += 256)
        bhist[blockIdx.x * KB_MAX + i] = h[i];
}

// ---------------------------------------------------------------- stage 2a: per-bucket scan of per-block
// counts (grid = K blocks, 256 threads = NBLK_BIN). Converts bhist[blk][b] in place into the
// exclusive offset of block blk RELATIVE to bucket b's start; writes bucket total to btot[b].
__global__ __launch_bounds__(256) void blockscan_kernel(
    int* __restrict__ bhist, int* __restrict__ btot) {
    __shared__ int wsum[4];
    const int b = blockIdx.x;
    const int t = threadIdx.x;                  // = source block index
    const int s = bhist[t * KB_MAX + b];
    int v = s;
    #pragma unroll
    for (int d = 1; d < 64; d <<= 1) {
        int u = __shfl_up(v, (unsigned)d, 64);
        if ((t & 63) >= d) v += u;
    }
    if ((t & 63) == 63) wsum[t >> 6] = v;
    __syncthreads();
    int off = 0;
    #pragma unroll
    for (int i = 0; i < 4; ++i) if (i < (t >> 6)) off += wsum[i];
    bhist[t * KB_MAX + b] = off + v - s;        // exclusive, bucket-relative
    if (t == 255) btot[b] = off + v;            // bucket total
}

// ---------------------------------------------------------------- stage 2b: scan bucket totals (1 block)
__global__ __launch_bounds__(256) void total_scan_kernel(
    const int* __restrict__ btot, int* __restrict__ bbase,
    int* __restrict__ rowptr, int E, int K, int N) {
    __shared__ int wsum[4];
    const int t = threadIdx.x;
    const int s = (t < K) ? btot[t] : 0;
    int v = s;
    #pragma unroll
    for (int d = 1; d < 64; d <<= 1) {
        int u = __shfl_up(v, (unsigned)d, 64);
        if ((t & 63) >= d) v += u;
    }
    if ((t & 63) == 63) wsum[t >> 6] = v;
    __syncthreads();
    int off = 0;
    #pragma unroll
    for (int i = 0; i < 4; ++i) if (i < (t >> 6)) off += wsum[i];
    const int excl = off + v - s;
    if (t < K) bbase[t] = excl;
    if (t == 0) { bbase[K] = E; rowptr[N] = E; }
}

// ---------------------------------------------------------------- stage 3: direct binned scatter
// Block-private prescanned ranges -> per-edge: one LDS cursor bump + one 8 B store.
// payload: word0 = col | (r_local << 17), word1 = val fp32
__global__ __launch_bounds__(256) void bin_kernel(
    const int* __restrict__ ei, const float* __restrict__ ea,
    const int* __restrict__ bloc, const int* __restrict__ bbase,
    int2* __restrict__ gbuf, int E, int K) {
    __shared__ int cur[KB_MAX];
    for (int i = threadIdx.x; i < K; i += 256)
        cur[i] = bbase[i] + bloc[blockIdx.x * KB_MAX + i];
    __syncthreads();
    const int chunk = (E + NBLK_BIN - 1) / NBLK_BIN;
    const int s0 = blockIdx.x * chunk;
    const int e0 = min(s0 + chunk, E);
    for (int j = s0 + threadIdx.x; j < e0; j += 256) {
        const int r = __builtin_nontemporal_load(ei + j);
        const int c = __builtin_nontemporal_load(ei + E + j);
        const int vv = __float_as_int(__builtin_nontemporal_load(ea + j));
        const int b = r >> RPB_BITS;
        const int gp = atomicAdd(&cur[b], 1);
        gbuf[gp] = make_int2(c | ((r & (RPB - 1)) << 17), vv);
    }
}

// ---------------------------------------------------------------- stage 4: per-bucket sort (phase B)
// 1024 threads/block (grid K < #CUs: each block owns its CU); bucket's edges cached
// in LDS (ECAP slots, global fallback); LDS count -> scan -> place. Emits rowptr.
__global__ __launch_bounds__(1024) void sort_kernel(
    const int* __restrict__ bbase, const int2* __restrict__ gbuf,
    int2* __restrict__ ecv, int* __restrict__ rowptr, int N) {
    __shared__ int2 ebuf[ECAP];      // 48 KB
    __shared__ int cnt[RPB];         // 2 KB, reused as next-cursor after scan
    __shared__ int wsum[8];
    const int b = blockIdx.x;
    const int t = threadIdx.x;
    const int bstart = bbase[b], bend = bbase[b + 1];
    const int m = bend - bstart;
    const int row0 = b << RPB_BITS;
    if (t < RPB) cnt[t] = 0;
    __syncthreads();
    for (int j = t; j < m; j += 1024) {
        const int2 p = gbuf[bstart + j];
        if (j < ECAP) ebuf[j] = p;
        atomicAdd(&cnt[(p.x >> 17) & (RPB - 1)], 1);
    }
    __syncthreads();
    int v = 0, s = 0;
    if (t < RPB) {
        s = cnt[t];
        v = s;
        #pragma unroll
        for (int d = 1; d < 64; d <<= 1) {
            int u = __shfl_up(v, (unsigned)d, 64);
            if ((t & 63) >= d) v += u;
        }
        if ((t & 63) == 63) wsum[t >> 6] = v;
    }
    __syncthreads();
    if (t < RPB) {
        int off = 0;
        #pragma unroll
        for (int i = 0; i < 8; ++i) if (i < (t >> 6)) off += wsum[i];
        const int excl = off + v - s;
        const int r0 = row0 + t;
        if (r0 < N) rowptr[r0] = bstart + excl;
        cnt[t] = excl;               // becomes the per-row placement cursor
    }
    __syncthreads();
    for (int j = t; j < m; j += 1024) {
        const int2 p = (j < ECAP) ? ebuf[j] : gbuf[bstart + j];
        const int lr = (p.x >> 17) & (RPB - 1);
        const int pos = atomicAdd(&cnt[lr], 1);
        ecv[bstart + pos] = make_int2(p.x & 0x1FFFF, p.y);
    }
}

// ---------------------------------------------------------------- pass 1
// 4 rows per wave (16 lanes/row, 4 features/lane via uint4): one wave VMEM
// instruction gathers 4 edges x 256 B; 16 edge-gathers in flight per wave.
__global__ __launch_bounds__(256) void pass1_kernel(
    const int* __restrict__ rowptr, const int2* __restrict__ ecv,
    const uint* __restrict__ H2,
    const float* __restrict__ b0, const float* __restrict__ fc0,
    const float* __restrict__ bf0,
    float* __restrict__ out, ushort* __restrict__ T16,
    float* __restrict__ dg1, int N) {
    const int lane = threadIdx.x & 63;
    const int g    = lane >> 4;
    const int l    = lane & 15;
    const int r = blockIdx.x * 16 + (threadIdx.x >> 6) * 4 + g;
    if (r >= N) return;
    const int f0 = l * 4;
    const uint* __restrict__ H2b = H2 + f0;
    const int jb = rowptr[r], je = rowptr[r + 1];

    float s00 = 0.f, s01 = 0.f, s02 = 0.f, s03 = 0.f;   // hop0 (lo)
    float s10 = 0.f, s11 = 0.f, s12 = 0.f, s13 = 0.f;   // hop1 (hi)
    float d = 0.f;
    int j = jb;
    for (; j + 4 <= je; j += 4) {
        const int2 e0 = ecv[j], e1 = ecv[j + 1], e2 = ecv[j + 2], e3 = ecv[j + 3];
        const uint4 h0 = *(const uint4*)(H2b + (size_t)e0.x * F_HOP);
        const uint4 h1 = *(const uint4*)(H2b + (size_t)e1.x * F_HOP);
        const uint4 h2 = *(const uint4*)(H2b + (size_t)e2.x * F_HOP);
        const uint4 h3 = *(const uint4*)(H2b + (size_t)e3.x * F_HOP);
        const float v0 = __int_as_float(e0.y), v1 = __int_as_float(e1.y);
        const float v2 = __int_as_float(e2.y), v3 = __int_as_float(e3.y);
        d += (v0 + v1) + (v2 + v3);
        s00 = fmaf(v0, bf_lo(h0.x), s00); s10 = fmaf(v0, bf_hi(h0.x), s10);
        s01 = fmaf(v0, bf_lo(h0.y), s01); s11 = fmaf(v0, bf_hi(h0.y), s11);
        s02 = fmaf(v0, bf_lo(h0.z), s02); s12 = fmaf(v0, bf_hi(h0.z), s12);
        s03 = fmaf(v0, bf_lo(h0.w), s03); s13 = fmaf(v0, bf_hi(h0.w), s13);
        s00 = fmaf(v1, bf_lo(h1.x), s00); s10 = fmaf(v1, bf_hi(h1.x), s10);
        s01 = fmaf(v1, bf_lo(h1.y), s01); s11 = fmaf(v1, bf_hi(h1.y), s11);
        s02 = fmaf(v1, bf_lo(h1.z), s02); s12 = fmaf(v1, bf_hi(h1.z), s12);
        s03 = fmaf(v1, bf_lo(h1.w), s03); s13 = fmaf(v1, bf_hi(h1.w), s13);
        s00 = fmaf(v2, bf_lo(h2.x), s00); s10 = fmaf(v2, bf_hi(h2.x), s10);
        s01 = fmaf(v2, bf_lo(h2.y), s01); s11 = fmaf(v2, bf_hi(h2.y), s11);
        s02 = fmaf(v2, bf_lo(h2.z), s02); s12 = fmaf(v2, bf_hi(h2.z), s12);
        s03 = fmaf(v2, bf_lo(h2.w), s03); s13 = fmaf(v2, bf_hi(h2.w), s13);
        s00 = fmaf(v3, bf_lo(h3.x), s00); s10 = fmaf(v3, bf_hi(h3.x), s10);
        s01 = fmaf(v3, bf_lo(h3.y), s01); s11 = fmaf(v3, bf_hi(h3.y), s11);
        s02 = fmaf(v3, bf_lo(h3.z), s02); s12 = fmaf(v3, bf_hi(h3.z), s12);
        s03 = fmaf(v3, bf_lo(h3.w), s03); s13 = fmaf(v3, bf_hi(h3.w), s13);
    }
    for (; j < je; ++j) {
        const int2 e0 = ecv[j];
        const uint4 h0 = *(const uint4*)(H2b + (size_t)e0.x * F_HOP);
        const float v0 = __int_as_float(e0.y);
        d += v0;
        s00 = fmaf(v0, bf_lo(h0.x), s00); s10 = fmaf(v0, bf_hi(h0.x), s10);
        s01 = fmaf(v0, bf_lo(h0.y), s01); s11 = fmaf(v0, bf_hi(h0.y), s11);
        s02 = fmaf(v0, bf_lo(h0.z), s02); s12 = fmaf(v0, bf_hi(h0.z), s12);
        s03 = fmaf(v0, bf_lo(h0.w), s03); s13 = fmaf(v0, bf_hi(h0.w), s13);
    }

    // T16: raw hop1 partial (A h1), bf16, 4 features per lane (re-read by pass2: keep cached)
    uint2 tw;
    tw.x = pack_bf16(s10, s11);
    tw.y = pack_bf16(s12, s13);
    *(uint2*)(T16 + (size_t)r * F_HOP + f0) = tw;
    if (l == 0) dg1[r] = d;

    const float inv = (d > 0.f) ? 1.f / d : 0.f;
    const float4 bb = *(const float4*)(b0 + f0);
    const float4 ff = *(const float4*)(fc0 + f0);
    const float y0 = s00 * inv + bb.x;
    const float y1 = s01 * inv + bb.y;
    const float y2 = s02 * inv + bb.z;
    const float y3 = s03 * inv + bb.w;
    float t = y0 * ff.x + y1 * ff.y + y2 * ff.z + y3 * ff.w;
    #pragma unroll
    for (int m = 1; m < 16; m <<= 1) t += __shfl_xor(t, m, 64);
    const float gg = 1.f / (1.f + __expf(-(t + bf0[0])));
    float4v o;
    o[0] = fmaxf(y0, 0.f) + gg * fminf(y0, 0.f);
    o[1] = fmaxf(y1, 0.f) + gg * fminf(y1, 0.f);
    o[2] = fmaxf(y2, 0.f) + gg * fminf(y2, 0.f);
    o[3] = fmaxf(y3, 0.f) + gg * fminf(y3, 0.f);
    __builtin_nontemporal_store(o, (float4v*)(out + (size_t)r * F_ALL + f0));
}

// ---------------------------------------------------------------- pass 2
// same 4-rows-per-wave layout: lane loads uint2 (4 bf16) of T16 per edge.
__global__ __launch_bounds__(256) void pass2_kernel(
    const int* __restrict__ rowptr, const int2* __restrict__ ecv,
    const ushort* __restrict__ T16, const float* __restrict__ dg1,
    const float* __restrict__ b1, const float* __restrict__ fc1,
    const float* __restrict__ bf1,
    float* __restrict__ out, int N) {
    const int lane = threadIdx.x & 63;
    const int g    = lane >> 4;
    const int l    = lane & 15;
    const int r = blockIdx.x * 16 + (threadIdx.x >> 6) * 4 + g;
    if (r >= N) return;
    const int f0 = l * 4;
    const ushort* __restrict__ Tb = T16 + f0;
    const int jb = rowptr[r], je = rowptr[r + 1];

    float s0 = 0.f, s1 = 0.f, s2 = 0.f, s3 = 0.f;
    float d2 = 0.f;
    int j = jb;
    for (; j + 4 <= je; j += 4) {
        const int2 e0 = ecv[j], e1 = ecv[j + 1], e2 = ecv[j + 2], e3 = ecv[j + 3];
        const uint2 t0 = *(const uint2*)(Tb + (size_t)e0.x * F_HOP);
        const uint2 t1 = *(const uint2*)(Tb + (size_t)e1.x * F_HOP);
        const uint2 t2 = *(const uint2*)(Tb + (size_t)e2.x * F_HOP);
        const uint2 t3 = *(const uint2*)(Tb + (size_t)e3.x * F_HOP);
        const float g0 = dg1[e0.x], g1 = dg1[e1.x], g2 = dg1[e2.x], g3 = dg1[e3.x];
        const float v0 = __int_as_float(e0.y), v1 = __int_as_float(e1.y);
        const float v2 = __int_as_float(e2.y), v3 = __int_as_float(e3.y);
        d2 = fmaf(v0, g0, d2); d2 = fmaf(v1, g1, d2);
        d2 = fmaf(v2, g2, d2); d2 = fmaf(v3, g3, d2);
        s0 = fmaf(v0, bf_lo(t0.x), s0); s1 = fmaf(v0, bf_hi(t0.x), s1);
        s2 = fmaf(v0, bf_lo(t0.y), s2); s3 = fmaf(v0, bf_hi(t0.y), s3);
        s0 = fmaf(v1, bf_lo(t1.x), s0); s1 = fmaf(v1, bf_hi(t1.x), s1);
        s2 = fmaf(v1, bf_lo(t1.y), s2); s3 = fmaf(v1, bf_hi(t1.y), s3);
        s0 = fmaf(v2, bf_lo(t2.x), s0); s1 = fmaf(v2, bf_hi(t2.x), s1);
        s2 = fmaf(v2, bf_lo(t2.y), s2); s3 = fmaf(v2, bf_hi(t2.y), s3);
        s0 = fmaf(v3, bf_lo(t3.x), s0); s1 = fmaf(v3, bf_hi(t3.x), s1);
        s2 = fmaf(v3, bf_lo(t3.y), s2); s3 = fmaf(v3, bf_hi(t3.y), s3);
    }
    for (; j < je; ++j) {
        const int2 e0 = ecv[j];
        const uint2 t0 = *(const uint2*)(Tb + (size_t)e0.x * F_HOP);
        const float v0 = __int_as_float(e0.y);
        d2 = fmaf(v0, dg1[e0.x], d2);
        s0 = fmaf(v0, bf_lo(t0.x), s0); s1 = fmaf(v0, bf_hi(t0.x), s1);
        s2 = fmaf(v0, bf_lo(t0.y), s2); s3 = fmaf(v0, bf_hi(t0.y), s3);
    }

    const float inv = (d2 > 0.f) ? 1.f / d2 : 0.f;
    const float4 bb = *(const float4*)(b1 + f0);
    const float4 ff = *(const float4*)(fc1 + f0);
    const float y0 = s0 * inv + bb.x;
    const float y1 = s1 * inv + bb.y;
    const float y2 = s2 * inv + bb.z;
    const float y3 = s3 * inv + bb.w;
    float t = y0 * ff.x + y1 * ff.y + y2 * ff.z + y3 * ff.w;
    #pragma unroll
    for (int m = 1; m < 16; m <<= 1) t += __shfl_xor(t, m, 64);
    const float gg = 1.f / (1.f + __expf(-(t + bf1[0])));
    float4v o;
    o[0] = fmaxf(y0, 0.f) + gg * fminf(y0, 0.f);
    o[1] = fmaxf(y1, 0.f) + gg * fminf(y1, 0.f);
    o[2] = fmaxf(y2, 0.f) + gg * fminf(y2, 0.f);
    o[3] = fmaxf(y3, 0.f) + gg * fminf(y3, 0.f);
    __builtin_nontemporal_store(o, (float4v*)(out + (size_t)r * F_ALL + F_HOP + f0));
}

// ---------------------------------------------------------------- launch
extern "C" void kernel_launch(void* const* d_in, const int* in_sizes, int n_in,
                              void* d_out, int out_size, void* d_ws, size_t ws_size,
                              hipStream_t stream) {
    const float* x   = (const float*)d_in[0];
    const int*   ei  = (const int*)  d_in[1];
    const float* ea  = (const float*)d_in[2];
    const float* W0  = (const float*)d_in[3];
    const float* b0  = (const float*)d_in[4];
    const float* W1  = (const float*)d_in[5];
    const float* b1  = (const float*)d_in[6];
    const float* fc0 = (const float*)d_in[7];
    const float* bf0 = (const float*)d_in[8];
    const float* fc1 = (const float*)d_in[9];
    const float* bf1 = (const float*)d_in[10];
    float* out = (float*)d_out;

    const int N = in_sizes[0] / F_IN;
    const int E = in_sizes[2];
    const int K = (N + RPB - 1) >> RPB_BITS;   // coarse buckets (<= KB_MAX)

    // workspace layout (4-byte units, regions 16B-aligned)
    uint*   H2   = (uint*)d_ws;                                  // N*64
    ushort* T16  = (ushort*)(H2 + (size_t)N * F_HOP);            // N*64 u16
    float*  dg1  = (float*)(T16 + (size_t)N * F_HOP);            // N
    int2*   gbuf = (int2*)(dg1 + (size_t)((N + 3) & ~3));        // E (bucketed edges)
    int2*   ecv  = gbuf + (size_t)E;                             // E (row-sorted edges)
    int*    bhist = (int*)(ecv + (size_t)E);                     // NBLK_BIN*KB_MAX
    int*    bbase = bhist + (size_t)NBLK_BIN * KB_MAX;           // K+1
    int*    btot  = bbase + (KB_MAX + 4);                        // K
    int*    rowptr = btot + KB_MAX;                              // N+1

    gemm_mfma_kernel<<<(N + 63) / 64, 256, 0, stream>>>(x, W0, W1, H2, N);

    bucket_hist_kernel<<<NBLK_BIN, 256, 0, stream>>>(ei, bhist, E, K);
    blockscan_kernel<<<K, 256, 0, stream>>>(bhist, btot);
    total_scan_kernel<<<1, 256, 0, stream>>>(btot, bbase, rowptr, E, K, N);
    bin_kernel<<<NBLK_BIN, 256, 0, stream>>>(ei, ea, bhist, bbase, gbuf, E, K);
    sort_kernel<<<K, 1024, 0, stream>>>(bbase, gbuf, ecv, rowptr, N);

    pass1_kernel<<<(N + 15) / 16, 256, 0, stream>>>(
        rowptr, ecv, H2, b0, fc0, bf0, out, T16, dg1, N);

    pass2_kernel<<<(N + 15) / 16, 256, 0, stream>>>(
        rowptr, ecv, T16, dg1, b1, fc1, bf1, out, N);
}

// Round 6
// 234.860 us; speedup vs baseline: 1.0187x; 1.0187x over previous
//
#include <hip/hip_runtime.h>

#define F_IN 128
#define F_ALL 128
#define F_HOP 64

#define RPB_BITS 8
#define RPB 256            // rows per bucket
#define KB_MAX 512         // max buckets (N <= 131072)
#define NBLK_BIN 256       // blocks for hist/bin kernels (== threads in blockscan)
#define ECAP 3072          // LDS edge-cache slots in sort kernel (24 KB)

typedef unsigned int uint;
typedef unsigned short ushort;
typedef __attribute__((ext_vector_type(8))) short short8v;
typedef __attribute__((ext_vector_type(4))) float float4v;

// ---------------------------------------------------------------- helpers
__device__ __forceinline__ uint pack_bf16(float lo, float hi) {
    uint ul = __float_as_uint(lo), uh = __float_as_uint(hi);
    ul += 0x7FFFu + ((ul >> 16) & 1u);
    uh += 0x7FFFu + ((uh >> 16) & 1u);
    return (ul >> 16) | (uh & 0xFFFF0000u);
}
__device__ __forceinline__ float bf_lo(uint h) { return __uint_as_float(h << 16); }
__device__ __forceinline__ float bf_hi(uint h) { return __uint_as_float(h & 0xFFFF0000u); }

// ---------------------------------------------------------------- MFMA GEMM + bf16 pack, fused with
// bucket histogram (independent work: hist blocks ride along after the gemm blocks).
__global__ __launch_bounds__(256) void gemm_hist_kernel(
    const float* __restrict__ x, const float* __restrict__ W0,
    const float* __restrict__ W1, uint* __restrict__ H2,
    const int* __restrict__ ei, int* __restrict__ bhist,
    int N, int E, int K, int gemmBlocks) {
    __shared__ ushort Wlds[16384];    // 32 KB (gemm); aliased as int[] by hist

    if ((int)blockIdx.x >= gemmBlocks) {
        // ---------------- histogram branch
        int* h = (int*)Wlds;
        const int hb = blockIdx.x - gemmBlocks;
        for (int i = threadIdx.x; i < K; i += 256) h[i] = 0;
        __syncthreads();
        const int chunk = (E + NBLK_BIN - 1) / NBLK_BIN;
        const int s = hb * chunk;
        const int e = min(s + chunk, E);
        for (int j = s + threadIdx.x; j < e; j += 256)
            atomicAdd(&h[__builtin_nontemporal_load(ei + j) >> RPB_BITS], 1);
        __syncthreads();
        for (int i = threadIdx.x; i < K; i += 256)
            bhist[hb * KB_MAX + i] = h[i];
        return;
    }

    // ---------------- gemm branch
    {
        const int t = threadIdx.x;
        #pragma unroll
        for (int i = 0; i < 8; ++i) {
            const int e    = t + 256 * i;
            const int lane = e & 63;
            const int tile = e >> 6;
            const int kt   = tile >> 3;
            const int nt   = tile & 7;
            const int k0   = kt * 32 + (lane >> 4) * 8;
            const int n    = nt * 16 + (lane & 15);
            const float* src = (n < 64) ? (W0 + n) : (W1 + (n - 64));
            float v[8];
            #pragma unroll
            for (int j = 0; j < 8; ++j) v[j] = src[(size_t)(k0 + j) * F_HOP];
            uint4 o;
            o.x = pack_bf16(v[0], v[1]);
            o.y = pack_bf16(v[2], v[3]);
            o.z = pack_bf16(v[4], v[5]);
            o.w = pack_bf16(v[6], v[7]);
            *((uint4*)Wlds + e) = o;
        }
    }
    __syncthreads();

    const int wv   = threadIdx.x >> 6;
    const int lane = threadIdx.x & 63;
    const int rbase = blockIdx.x * 64 + wv * 16;
    if (rbase >= N) return;

    const int m    = lane & 15;
    const int quad = lane >> 4;
    const float* xrow = x + (size_t)(rbase + m) * F_IN + quad * 8;

    float4v acc[8];
    #pragma unroll
    for (int t = 0; t < 8; ++t) acc[t] = (float4v){0.f, 0.f, 0.f, 0.f};

    #pragma unroll
    for (int kt = 0; kt < 4; ++kt) {
        // x is single-use: nontemporal
        const float4v xa = __builtin_nontemporal_load((const float4v*)(xrow + kt * 32));
        const float4v xb = __builtin_nontemporal_load((const float4v*)(xrow + kt * 32 + 4));
        union { uint4 u; short8v s; } av;
        av.u.x = pack_bf16(xa[0], xa[1]);
        av.u.y = pack_bf16(xa[2], xa[3]);
        av.u.z = pack_bf16(xb[0], xb[1]);
        av.u.w = pack_bf16(xb[2], xb[3]);
        #pragma unroll
        for (int nt = 0; nt < 8; ++nt) {
            union { uint4 u; short8v s; } bv;
            bv.u = *((const uint4*)Wlds + (kt * 8 + nt) * 64 + lane);
            acc[nt] = __builtin_amdgcn_mfma_f32_16x16x32_bf16(av.s, bv.s, acc[nt], 0, 0, 0);
        }
    }

    #pragma unroll
    for (int t = 0; t < 4; ++t) {
        #pragma unroll
        for (int i = 0; i < 4; ++i) {
            const int r = rbase + quad * 4 + i;
            H2[(size_t)r * F_HOP + t * 16 + m] = pack_bf16(acc[t][i], acc[t + 4][i]);
        }
    }
}

// ---------------------------------------------------------------- stage 2: per-bucket scan of per-block
// counts (grid = K blocks, 256 threads = NBLK_BIN). Converts bhist[blk][b] in place into the
// exclusive offset of block blk RELATIVE to bucket b's start; writes bucket total to btot[b].
__global__ __launch_bounds__(256) void blockscan_kernel(
    int* __restrict__ bhist, int* __restrict__ btot,
    int* __restrict__ rowptr, int E, int N) {
    __shared__ int wsum[4];
    const int b = blockIdx.x;
    const int t = threadIdx.x;                  // = source block index
    const int s = bhist[t * KB_MAX + b];
    int v = s;
    #pragma unroll
    for (int d = 1; d < 64; d <<= 1) {
        int u = __shfl_up(v, (unsigned)d, 64);
        if ((t & 63) >= d) v += u;
    }
    if ((t & 63) == 63) wsum[t >> 6] = v;
    __syncthreads();
    int off = 0;
    #pragma unroll
    for (int i = 0; i < 4; ++i) if (i < (t >> 6)) off += wsum[i];
    bhist[t * KB_MAX + b] = off + v - s;        // exclusive, bucket-relative
    if (t == 255) btot[b] = off + v;            // bucket total
    if (b == 0 && t == 0) rowptr[N] = E;
}

// ---------------------------------------------------------------- stage 3: direct binned scatter
// bbase (exclusive scan of btot over K <= 512 buckets) recomputed per-block in LDS
// (2 KB from L2: cheap, parallel) -> total_scan kernel eliminated.
// payload: word0 = col | (r_local << 17), word1 = val fp32
__global__ __launch_bounds__(256) void bin_kernel(
    const int* __restrict__ ei, const float* __restrict__ ea,
    const int* __restrict__ bloc, const int* __restrict__ btot,
    int2* __restrict__ gbuf, int E, int K) {
    __shared__ int bb[KB_MAX];
    __shared__ int cur[KB_MAX];
    __shared__ int wsum[4];
    const int t = threadIdx.x;
    // pair-scan over K entries with 256 threads
    const int i0 = 2 * t, i1 = 2 * t + 1;
    const int c0 = (i0 < K) ? btot[i0] : 0;
    const int c1 = (i1 < K) ? btot[i1] : 0;
    const int s = c0 + c1;
    int v = s;
    #pragma unroll
    for (int d = 1; d < 64; d <<= 1) {
        int u = __shfl_up(v, (unsigned)d, 64);
        if ((t & 63) >= d) v += u;
    }
    if ((t & 63) == 63) wsum[t >> 6] = v;
    __syncthreads();
    {
        int off = 0;
        #pragma unroll
        for (int i = 0; i < 4; ++i) if (i < (t >> 6)) off += wsum[i];
        const int excl = off + v - s;
        if (i0 < K) bb[i0] = excl;
        if (i1 < K) bb[i1] = excl + c0;
    }
    __syncthreads();
    for (int i = t; i < K; i += 256)
        cur[i] = bb[i] + bloc[blockIdx.x * KB_MAX + i];
    __syncthreads();
    const int chunk = (E + NBLK_BIN - 1) / NBLK_BIN;
    const int s0 = blockIdx.x * chunk;
    const int e0 = min(s0 + chunk, E);
    for (int j = s0 + t; j < e0; j += 256) {
        const int r = __builtin_nontemporal_load(ei + j);
        const int c = __builtin_nontemporal_load(ei + E + j);
        const int vv = __float_as_int(__builtin_nontemporal_load(ea + j));
        const int b = r >> RPB_BITS;
        const int gp = atomicAdd(&cur[b], 1);
        gbuf[gp] = make_int2(c | ((r & (RPB - 1)) << 17), vv);
    }
}

// ---------------------------------------------------------------- stage 4: per-bucket sort
// grid = K (391 at N=100k) blocks x 512 threads; bucket edges cached in LDS; bbase
// recomputed in-block from btot. LDS count -> scan -> place. Emits rowptr.
__global__ __launch_bounds__(512) void sort_kernel(
    const int* __restrict__ btot, const int2* __restrict__ gbuf,
    int2* __restrict__ ecv, int* __restrict__ rowptr, int E, int K, int N) {
    __shared__ int2 ebuf[ECAP];      // 24 KB
    __shared__ int cnt[RPB];         // 1 KB, reused as next-cursor after scan
    __shared__ int bb[KB_MAX + 1];   // 2 KB
    __shared__ int wsum[4];
    const int b = blockIdx.x;
    const int t = threadIdx.x;
    // 1) bb = exclusive scan of btot (threads 0..255, pair trick)
    const int i0 = 2 * t, i1 = 2 * t + 1;
    const int c0 = (t < 256 && i0 < K) ? btot[i0] : 0;
    const int c1 = (t < 256 && i1 < K) ? btot[i1] : 0;
    const int s = c0 + c1;
    int v = s;
    #pragma unroll
    for (int d = 1; d < 64; d <<= 1) {
        int u = __shfl_up(v, (unsigned)d, 64);
        if ((t & 63) >= d) v += u;
    }
    if (t < 256 && (t & 63) == 63) wsum[t >> 6] = v;
    if (t < RPB) cnt[t] = 0;
    __syncthreads();
    if (t < 256) {
        int off = 0;
        #pragma unroll
        for (int i = 0; i < 4; ++i) if (i < (t >> 6)) off += wsum[i];
        const int excl = off + v - s;
        if (i0 < K) bb[i0] = excl;
        if (i1 < K) bb[i1] = excl + c0;
    }
    if (t == 0) bb[K] = E;
    __syncthreads();
    const int bstart = bb[b], bend = bb[b + 1];
    const int m = bend - bstart;
    const int row0 = b << RPB_BITS;
    // 2) count
    for (int j = t; j < m; j += 512) {
        const int2 p = gbuf[bstart + j];
        if (j < ECAP) ebuf[j] = p;
        atomicAdd(&cnt[(p.x >> 17) & (RPB - 1)], 1);
    }
    __syncthreads();
    // 3) scan cnt (256 entries, threads 0..255)
    const int s2 = (t < 256) ? cnt[t] : 0;
    int v2 = s2;
    #pragma unroll
    for (int d = 1; d < 64; d <<= 1) {
        int u = __shfl_up(v2, (unsigned)d, 64);
        if ((t & 63) >= d) v2 += u;
    }
    if (t < 256 && (t & 63) == 63) wsum[t >> 6] = v2;
    __syncthreads();
    int excl2 = 0;
    if (t < 256) {
        int off = 0;
        #pragma unroll
        for (int i = 0; i < 4; ++i) if (i < (t >> 6)) off += wsum[i];
        excl2 = off + v2 - s2;
        const int r0 = row0 + t;
        if (r0 < N) rowptr[r0] = bstart + excl2;
    }
    __syncthreads();
    if (t < 256) cnt[t] = excl2;     // becomes the per-row placement cursor
    __syncthreads();
    // 4) place
    for (int j = t; j < m; j += 512) {
        const int2 p = (j < ECAP) ? ebuf[j] : gbuf[bstart + j];
        const int lr = (p.x >> 17) & (RPB - 1);
        const int pos = atomicAdd(&cnt[lr], 1);
        ecv[bstart + pos] = make_int2(p.x & 0x1FFFF, p.y);
    }
}

// ---------------------------------------------------------------- pass 1
// 4 rows per wave (16 lanes/row, 4 features/lane via uint4): one wave VMEM
// instruction gathers 4 edges x 256 B; 16 edge-gathers in flight per wave.
__global__ __launch_bounds__(256) void pass1_kernel(
    const int* __restrict__ rowptr, const int2* __restrict__ ecv,
    const uint* __restrict__ H2,
    const float* __restrict__ b0, const float* __restrict__ fc0,
    const float* __restrict__ bf0,
    float* __restrict__ out, ushort* __restrict__ T16,
    float* __restrict__ dg1, int N) {
    const int lane = threadIdx.x & 63;
    const int g    = lane >> 4;
    const int l    = lane & 15;
    const int r = blockIdx.x * 16 + (threadIdx.x >> 6) * 4 + g;
    if (r >= N) return;
    const int f0 = l * 4;
    const uint* __restrict__ H2b = H2 + f0;
    const int jb = rowptr[r], je = rowptr[r + 1];

    float s00 = 0.f, s01 = 0.f, s02 = 0.f, s03 = 0.f;   // hop0 (lo)
    float s10 = 0.f, s11 = 0.f, s12 = 0.f, s13 = 0.f;   // hop1 (hi)
    float d = 0.f;
    int j = jb;
    for (; j + 4 <= je; j += 4) {
        const int2 e0 = ecv[j], e1 = ecv[j + 1], e2 = ecv[j + 2], e3 = ecv[j + 3];
        const uint4 h0 = *(const uint4*)(H2b + (size_t)e0.x * F_HOP);
        const uint4 h1 = *(const uint4*)(H2b + (size_t)e1.x * F_HOP);
        const uint4 h2 = *(const uint4*)(H2b + (size_t)e2.x * F_HOP);
        const uint4 h3 = *(const uint4*)(H2b + (size_t)e3.x * F_HOP);
        const float v0 = __int_as_float(e0.y), v1 = __int_as_float(e1.y);
        const float v2 = __int_as_float(e2.y), v3 = __int_as_float(e3.y);
        d += (v0 + v1) + (v2 + v3);
        s00 = fmaf(v0, bf_lo(h0.x), s00); s10 = fmaf(v0, bf_hi(h0.x), s10);
        s01 = fmaf(v0, bf_lo(h0.y), s01); s11 = fmaf(v0, bf_hi(h0.y), s11);
        s02 = fmaf(v0, bf_lo(h0.z), s02); s12 = fmaf(v0, bf_hi(h0.z), s12);
        s03 = fmaf(v0, bf_lo(h0.w), s03); s13 = fmaf(v0, bf_hi(h0.w), s13);
        s00 = fmaf(v1, bf_lo(h1.x), s00); s10 = fmaf(v1, bf_hi(h1.x), s10);
        s01 = fmaf(v1, bf_lo(h1.y), s01); s11 = fmaf(v1, bf_hi(h1.y), s11);
        s02 = fmaf(v1, bf_lo(h1.z), s02); s12 = fmaf(v1, bf_hi(h1.z), s12);
        s03 = fmaf(v1, bf_lo(h1.w), s03); s13 = fmaf(v1, bf_hi(h1.w), s13);
        s00 = fmaf(v2, bf_lo(h2.x), s00); s10 = fmaf(v2, bf_hi(h2.x), s10);
        s01 = fmaf(v2, bf_lo(h2.y), s01); s11 = fmaf(v2, bf_hi(h2.y), s11);
        s02 = fmaf(v2, bf_lo(h2.z), s02); s12 = fmaf(v2, bf_hi(h2.z), s12);
        s03 = fmaf(v2, bf_lo(h2.w), s03); s13 = fmaf(v2, bf_hi(h2.w), s13);
        s00 = fmaf(v3, bf_lo(h3.x), s00); s10 = fmaf(v3, bf_hi(h3.x), s10);
        s01 = fmaf(v3, bf_lo(h3.y), s01); s11 = fmaf(v3, bf_hi(h3.y), s11);
        s02 = fmaf(v3, bf_lo(h3.z), s02); s12 = fmaf(v3, bf_hi(h3.z), s12);
        s03 = fmaf(v3, bf_lo(h3.w), s03); s13 = fmaf(v3, bf_hi(h3.w), s13);
    }
    for (; j < je; ++j) {
        const int2 e0 = ecv[j];
        const uint4 h0 = *(const uint4*)(H2b + (size_t)e0.x * F_HOP);
        const float v0 = __int_as_float(e0.y);
        d += v0;
        s00 = fmaf(v0, bf_lo(h0.x), s00); s10 = fmaf(v0, bf_hi(h0.x), s10);
        s01 = fmaf(v0, bf_lo(h0.y), s01); s11 = fmaf(v0, bf_hi(h0.y), s11);
        s02 = fmaf(v0, bf_lo(h0.z), s02); s12 = fmaf(v0, bf_hi(h0.z), s12);
        s03 = fmaf(v0, bf_lo(h0.w), s03); s13 = fmaf(v0, bf_hi(h0.w), s13);
    }

    // T16: raw hop1 partial (A h1), bf16, 4 features per lane (re-read by pass2: keep cached)
    uint2 tw;
    tw.x = pack_bf16(s10, s11);
    tw.y = pack_bf16(s12, s13);
    *(uint2*)(T16 + (size_t)r * F_HOP + f0) = tw;
    if (l == 0) dg1[r] = d;

    const float inv = (d > 0.f) ? 1.f / d : 0.f;
    const float4 bb = *(const float4*)(b0 + f0);
    const float4 ff = *(const float4*)(fc0 + f0);
    const float y0 = s00 * inv + bb.x;
    const float y1 = s01 * inv + bb.y;
    const float y2 = s02 * inv + bb.z;
    const float y3 = s03 * inv + bb.w;
    float t = y0 * ff.x + y1 * ff.y + y2 * ff.z + y3 * ff.w;
    #pragma unroll
    for (int m = 1; m < 16; m <<= 1) t += __shfl_xor(t, m, 64);
    const float gg = 1.f / (1.f + __expf(-(t + bf0[0])));
    float4v o;
    o[0] = fmaxf(y0, 0.f) + gg * fminf(y0, 0.f);
    o[1] = fmaxf(y1, 0.f) + gg * fminf(y1, 0.f);
    o[2] = fmaxf(y2, 0.f) + gg * fminf(y2, 0.f);
    o[3] = fmaxf(y3, 0.f) + gg * fminf(y3, 0.f);
    __builtin_nontemporal_store(o, (float4v*)(out + (size_t)r * F_ALL + f0));
}

// ---------------------------------------------------------------- pass 2
// same 4-rows-per-wave layout: lane loads uint2 (4 bf16) of T16 per edge.
__global__ __launch_bounds__(256) void pass2_kernel(
    const int* __restrict__ rowptr, const int2* __restrict__ ecv,
    const ushort* __restrict__ T16, const float* __restrict__ dg1,
    const float* __restrict__ b1, const float* __restrict__ fc1,
    const float* __restrict__ bf1,
    float* __restrict__ out, int N) {
    const int lane = threadIdx.x & 63;
    const int g    = lane >> 4;
    const int l    = lane & 15;
    const int r = blockIdx.x * 16 + (threadIdx.x >> 6) * 4 + g;
    if (r >= N) return;
    const int f0 = l * 4;
    const ushort* __restrict__ Tb = T16 + f0;
    const int jb = rowptr[r], je = rowptr[r + 1];

    float s0 = 0.f, s1 = 0.f, s2 = 0.f, s3 = 0.f;
    float d2 = 0.f;
    int j = jb;
    for (; j + 4 <= je; j += 4) {
        const int2 e0 = ecv[j], e1 = ecv[j + 1], e2 = ecv[j + 2], e3 = ecv[j + 3];
        const uint2 t0 = *(const uint2*)(Tb + (size_t)e0.x * F_HOP);
        const uint2 t1 = *(const uint2*)(Tb + (size_t)e1.x * F_HOP);
        const uint2 t2 = *(const uint2*)(Tb + (size_t)e2.x * F_HOP);
        const uint2 t3 = *(const uint2*)(Tb + (size_t)e3.x * F_HOP);
        const float g0 = dg1[e0.x], g1 = dg1[e1.x], g2 = dg1[e2.x], g3 = dg1[e3.x];
        const float v0 = __int_as_float(e0.y), v1 = __int_as_float(e1.y);
        const float v2 = __int_as_float(e2.y), v3 = __int_as_float(e3.y);
        d2 = fmaf(v0, g0, d2); d2 = fmaf(v1, g1, d2);
        d2 = fmaf(v2, g2, d2); d2 = fmaf(v3, g3, d2);
        s0 = fmaf(v0, bf_lo(t0.x), s0); s1 = fmaf(v0, bf_hi(t0.x), s1);
        s2 = fmaf(v0, bf_lo(t0.y), s2); s3 = fmaf(v0, bf_hi(t0.y), s3);
        s0 = fmaf(v1, bf_lo(t1.x), s0); s1 = fmaf(v1, bf_hi(t1.x), s1);
        s2 = fmaf(v1, bf_lo(t1.y), s2); s3 = fmaf(v1, bf_hi(t1.y), s3);
        s0 = fmaf(v2, bf_lo(t2.x), s0); s1 = fmaf(v2, bf_hi(t2.x), s1);
        s2 = fmaf(v2, bf_lo(t2.y), s2); s3 = fmaf(v2, bf_hi(t2.y), s3);
        s0 = fmaf(v3, bf_lo(t3.x), s0); s1 = fmaf(v3, bf_hi(t3.x), s1);
        s2 = fmaf(v3, bf_lo(t3.y), s2); s3 = fmaf(v3, bf_hi(t3.y), s3);
    }
    for (; j < je; ++j) {
        const int2 e0 = ecv[j];
        const uint2 t0 = *(const uint2*)(Tb + (size_t)e0.x * F_HOP);
        const float v0 = __int_as_float(e0.y);
        d2 = fmaf(v0, dg1[e0.x], d2);
        s0 = fmaf(v0, bf_lo(t0.x), s0); s1 = fmaf(v0, bf_hi(t0.x), s1);
        s2 = fmaf(v0, bf_lo(t0.y), s2); s3 = fmaf(v0, bf_hi(t0.y), s3);
    }

    const float inv = (d2 > 0.f) ? 1.f / d2 : 0.f;
    const float4 bb = *(const float4*)(b1 + f0);
    const float4 ff = *(const float4*)(fc1 + f0);
    const float y0 = s0 * inv + bb.x;
    const float y1 = s1 * inv + bb.y;
    const float y2 = s2 * inv + bb.z;
    const float y3 = s3 * inv + bb.w;
    float t = y0 * ff.x + y1 * ff.y + y2 * ff.z + y3 * ff.w;
    #pragma unroll
    for (int m = 1; m < 16; m <<= 1) t += __shfl_xor(t, m, 64);
    const float gg = 1.f / (1.f + __expf(-(t + bf1[0])));
    float4v o;
    o[0] = fmaxf(y0, 0.f) + gg * fminf(y0, 0.f);
    o[1] = fmaxf(y1, 0.f) + gg * fminf(y1, 0.f);
    o[2] = fmaxf(y2, 0.f) + gg * fminf(y2, 0.f);
    o[3] = fmaxf(y3, 0.f) + gg * fminf(y3, 0.f);
    __builtin_nontemporal_store(o, (float4v*)(out + (size_t)r * F_ALL + F_HOP + f0));
}

// ---------------------------------------------------------------- launch
extern "C" void kernel_launch(void* const* d_in, const int* in_sizes, int n_in,
                              void* d_out, int out_size, void* d_ws, size_t ws_size,
                              hipStream_t stream) {
    const float* x   = (const float*)d_in[0];
    const int*   ei  = (const int*)  d_in[1];
    const float* ea  = (const float*)d_in[2];
    const float* W0  = (const float*)d_in[3];
    const float* b0  = (const float*)d_in[4];
    const float* W1  = (const float*)d_in[5];
    const float* b1  = (const float*)d_in[6];
    const float* fc0 = (const float*)d_in[7];
    const float* bf0 = (const float*)d_in[8];
    const float* fc1 = (const float*)d_in[9];
    const float* bf1 = (const float*)d_in[10];
    float* out = (float*)d_out;

    const int N = in_sizes[0] / F_IN;
    const int E = in_sizes[2];
    const int K = (N + RPB - 1) >> RPB_BITS;   // coarse buckets (<= KB_MAX)

    // workspace layout (4-byte units, regions 16B-aligned)
    uint*   H2   = (uint*)d_ws;                                  // N*64
    ushort* T16  = (ushort*)(H2 + (size_t)N * F_HOP);            // N*64 u16
    float*  dg1  = (float*)(T16 + (size_t)N * F_HOP);            // N
    int2*   gbuf = (int2*)(dg1 + (size_t)((N + 3) & ~3));        // E (bucketed edges)
    int2*   ecv  = gbuf + (size_t)E;                             // E (row-sorted edges)
    int*    bhist = (int*)(ecv + (size_t)E);                     // NBLK_BIN*KB_MAX
    int*    btot  = bhist + (size_t)NBLK_BIN * KB_MAX;           // K
    int*    rowptr = btot + (KB_MAX + 4);                        // N+1

    const int gemmBlocks = (N + 63) / 64;
    gemm_hist_kernel<<<gemmBlocks + NBLK_BIN, 256, 0, stream>>>(
        x, W0, W1, H2, ei, bhist, N, E, K, gemmBlocks);

    blockscan_kernel<<<K, 256, 0, stream>>>(bhist, btot, rowptr, E, N);
    bin_kernel<<<NBLK_BIN, 256, 0, stream>>>(ei, ea, bhist, btot, gbuf, E, K);
    sort_kernel<<<K, 512, 0, stream>>>(btot, gbuf, ecv, rowptr, E, K, N);

    pass1_kernel<<<(N + 15) / 16, 256, 0, stream>>>(
        rowptr, ecv, H2, b0, fc0, bf0, out, T16, dg1, N);

    pass2_kernel<<<(N + 15) / 16, 256, 0, stream>>>(
        rowptr, ecv, T16, dg1, b1, fc1, bf1, out, N);
}